// Round 6
// baseline (1042.355 us; speedup 1.0000x reference)
//
#include <hip/hip_runtime.h>

#define N_NODES 100000
#define N_EDGES 1600000
#define DIM 256

typedef unsigned short bf16u;
typedef __attribute__((ext_vector_type(8))) short bf16x8s;
typedef __attribute__((ext_vector_type(4))) float f32x4;

__device__ __forceinline__ float bf2f(unsigned int u16) {
    union { unsigned int i; float f; } x; x.i = u16 << 16; return x.f;
}
__device__ __forceinline__ bf16u f2bf(float f) {
    union { float f; unsigned int i; } x; x.f = f;
    unsigned int i = x.i;
    return (bf16u)((i + 0x7fffu + ((i >> 16) & 1u)) >> 16);
}
__device__ __forceinline__ float loadv(const void* p, size_t i, int isf32) {
    return isf32 ? ((const float*)p)[i] : bf2f(((const bf16u*)p)[i]);
}

// ---------------- zero helpers ----------------
__global__ void zero_ints(int* p, int n) {
    int i = blockIdx.x * 256 + threadIdx.x;
    if (i < n) p[i] = 0;
}
__global__ void zero_floats(float* p, int n) {
    int i = blockIdx.x * 256 + threadIdx.x;
    if (i < n) p[i] = 0.f;
}

// ---------------- runtime format probes ----------------
__global__ void detect_flags(const unsigned* xw, const int* ei, int* flags) {
    __shared__ int cnt, nz;
    if (threadIdx.x == 0) { cnt = 0; nz = 0; }
    __syncthreads();
    unsigned u = xw[threadIdx.x];
    float av = fabsf(bf2f(u & 0xffffu));
    if (av > 1e-5f && av < 50.f) atomicAdd(&cnt, 1);
    if (ei[2 * threadIdx.x + 1] != 0) atomicAdd(&nz, 1);
    __syncthreads();
    if (threadIdx.x == 0) {
        flags[0] = (cnt >= 128) ? 0 : 1;           // 1 = inputs are float32
        if (nz == 0) { flags[1] = 2; flags[2] = 2 * N_EDGES; }
        else         { flags[1] = 1; flags[2] = N_EDGES; }
    }
}

// ---------------- weight transpose: Wt[n][k] = bf16(W[k][n]) ----------------
__global__ void transpose_w(const void* W0, const void* W1, const void* W2, const void* W3,
                            bf16u* Wt, const int* flags) {
    __shared__ bf16u tile[64][65];
    int isf32 = flags[0];
    const void* W = (blockIdx.y == 0) ? W0 : (blockIdx.y == 1) ? W1 : (blockIdx.y == 2) ? W2 : W3;
    bf16u* out = Wt + (size_t)blockIdx.y * DIM * DIM;
    int t = threadIdx.x;
    int tx = t & 63, ty = t >> 6;
    int k0 = (blockIdx.x >> 2) * 64, n0 = (blockIdx.x & 3) * 64;
#pragma unroll
    for (int i = 0; i < 16; ++i) {
        int r = ty + i * 4;
        tile[tx][r] = f2bf(loadv(W, (size_t)(k0 + r) * DIM + (n0 + tx), isf32));
    }
    __syncthreads();
#pragma unroll
    for (int i = 0; i < 16; ++i) {
        int r = ty + i * 4;
        out[(size_t)(n0 + r) * DIM + (k0 + tx)] = tile[r][tx];
    }
}

// ---------------- BN0 column stats (dual dtype input) ----------------
__global__ void col_stats(const void* X, int nrows, float* sums, const int* flags, int dual) {
    __shared__ float ls[512];
    int isf32 = dual ? flags[0] : 0;
    int t = threadIdx.x;
    ls[t] = 0.f; ls[t + 256] = 0.f;
    __syncthreads();
    int rpb = (nrows + gridDim.x - 1) / gridDim.x;
    int r0 = blockIdx.x * rpb;
    int r1 = r0 + rpb; if (r1 > nrows) r1 = nrows;
    int cg = (t & 31) * 8;
    float s[8], q[8];
#pragma unroll
    for (int j = 0; j < 8; ++j) { s[j] = 0.f; q[j] = 0.f; }
    for (int r = r0 + (t >> 5); r < r1; r += 8) {
        size_t base = (size_t)r * DIM + cg;
#pragma unroll
        for (int j = 0; j < 8; ++j) {
            float f = loadv(X, base + j, isf32);
            s[j] += f; q[j] += f * f;
        }
    }
#pragma unroll
    for (int j = 0; j < 8; ++j) {
        atomicAdd(&ls[cg + j], s[j]);
        atomicAdd(&ls[256 + cg + j], q[j]);
    }
    __syncthreads();
    atomicAdd(&sums[t], ls[t]);
    atomicAdd(&sums[256 + t], ls[256 + t]);
}

__global__ void bn_finalize(const float* sums, const void* gamma, const void* beta,
                            float* sc, float* sh, float inv_n, const int* flags) {
    int isf32 = flags[0];
    int t = threadIdx.x;
    float mu = sums[t] * inv_n;
    float var = sums[256 + t] * inv_n - mu * mu;
    float rs = rsqrtf(var + 1e-5f);
    float g = loadv(gamma, t, isf32), b = loadv(beta, t, isf32);
    sc[t] = rs * g;
    sh[t] = b - mu * rs * g;
}

// ---------------- vectorized BN apply ----------------
__global__ void bn_apply(const void* X, const float* sc, const float* sh, bf16u* Y,
                         const int* flags, int dual, int relu) {
    int isf32 = dual ? flags[0] : 0;
    size_t i = (size_t)blockIdx.x * 256 + threadIdx.x;
    int c = ((int)(i & 31)) * 8;
    size_t base = i * 8;
    float v[8];
    if (isf32) {
        f32x4 x0 = *(const f32x4*)((const float*)X + base);
        f32x4 x1 = *(const f32x4*)((const float*)X + base + 4);
#pragma unroll
        for (int j = 0; j < 4; ++j) { v[j] = x0[j]; v[4 + j] = x1[j]; }
    } else {
        uint4 u = *(const uint4*)((const bf16u*)X + base);
        v[0] = bf2f(u.x & 0xffffu); v[1] = bf2f(u.x >> 16);
        v[2] = bf2f(u.y & 0xffffu); v[3] = bf2f(u.y >> 16);
        v[4] = bf2f(u.z & 0xffffu); v[5] = bf2f(u.z >> 16);
        v[6] = bf2f(u.w & 0xffffu); v[7] = bf2f(u.w >> 16);
    }
    f32x4 s0 = *(const f32x4*)(sc + c), s1 = *(const f32x4*)(sc + c + 4);
    f32x4 h0 = *(const f32x4*)(sh + c), h1 = *(const f32x4*)(sh + c + 4);
    float y[8];
#pragma unroll
    for (int j = 0; j < 4; ++j) {
        y[j]     = v[j]     * s0[j] + h0[j];
        y[4 + j] = v[4 + j] * s1[j] + h1[j];
    }
    if (relu) {
#pragma unroll
        for (int j = 0; j < 8; ++j) y[j] = fmaxf(y[j], 0.f);
    }
    uint4 ov;
    ov.x = (unsigned)f2bf(y[0]) | ((unsigned)f2bf(y[1]) << 16);
    ov.y = (unsigned)f2bf(y[2]) | ((unsigned)f2bf(y[3]) << 16);
    ov.z = (unsigned)f2bf(y[4]) | ((unsigned)f2bf(y[5]) << 16);
    ov.w = (unsigned)f2bf(y[6]) | ((unsigned)f2bf(y[7]) << 16);
    *(uint4*)(Y + base) = ov;
}

// ---------------- CSR build ----------------
__global__ void edge_hist(const int* ei, const int* flags, int* deg) {
    int e = blockIdx.x * 256 + threadIdx.x;
    if (e < N_EDGES) atomicAdd(&deg[ei[(size_t)flags[2] + (size_t)e * flags[1]]], 1);
}

__global__ void scan1(const int* deg, int* rp, int* bsum) {
    __shared__ int s[256];
    int t = threadIdx.x;
    int i = blockIdx.x * 256 + t;
    s[t] = (i < N_NODES) ? deg[i] : 0;
    __syncthreads();
    for (int off = 1; off < 256; off <<= 1) {
        int nv = (t >= off) ? s[t - off] : 0;
        __syncthreads();
        s[t] += nv;
        __syncthreads();
    }
    if (i < N_NODES) rp[i + 1] = s[t];
    if (t == 255) bsum[blockIdx.x] = s[255];
}

__global__ void scan2(int* bsum, int nblocks) {
    __shared__ int s[512];
    int t = threadIdx.x;
    s[t] = (t < nblocks) ? bsum[t] : 0;
    __syncthreads();
    for (int off = 1; off < 512; off <<= 1) {
        int nv = (t >= off) ? s[t - off] : 0;
        __syncthreads();
        s[t] += nv;
        __syncthreads();
    }
    if (t < nblocks) bsum[t] = s[t];
}

__global__ void scan3(int* rp, const int* bsum) {
    int i = blockIdx.x * 256 + threadIdx.x;
    if (i == 0) rp[0] = 0;
    if (i < N_NODES) {
        int b = i >> 8;
        if (b > 0) rp[i + 1] += bsum[b - 1];
    }
}

__global__ void csr_fill(const int* ei, const int* flags, const int* rp, int* fill, int* col) {
    int e = blockIdx.x * 256 + threadIdx.x;
    if (e < N_EDGES) {
        int d = ei[(size_t)flags[2] + (size_t)e * flags[1]];
        int s = ei[(size_t)e * flags[1]];
        int p = rp[d] + atomicAdd(&fill[d], 1);
        col[p] = s;
    }
}

// ---------------- aggregation, unroll-8 ----------------
__global__ void aggregate(const bf16u* h, const int* rp, const int* col, bf16u* out) {
    int node = blockIdx.x * 4 + (threadIdx.x >> 6);
    int lane = threadIdx.x & 63;
    const uint2* hv = (const uint2*)h;            // 8B units, 64 per row
    uint2 u = hv[(size_t)node * 64 + lane];
    float ax[8], ay[8], az[8], aw[8];
#pragma unroll
    for (int j = 0; j < 8; ++j) { ax[j] = 0.f; ay[j] = 0.f; az[j] = 0.f; aw[j] = 0.f; }
    ax[0] = bf2f(u.x & 0xffffu); ay[0] = bf2f(u.x >> 16);
    az[0] = bf2f(u.y & 0xffffu); aw[0] = bf2f(u.y >> 16);
    int e = rp[node], e1 = rp[node + 1];
    for (; e + 8 <= e1; e += 8) {
        uint2 w[8];
#pragma unroll
        for (int j = 0; j < 8; ++j) w[j] = hv[(size_t)col[e + j] * 64 + lane];
#pragma unroll
        for (int j = 0; j < 8; ++j) {
            ax[j] += bf2f(w[j].x & 0xffffu); ay[j] += bf2f(w[j].x >> 16);
            az[j] += bf2f(w[j].y & 0xffffu); aw[j] += bf2f(w[j].y >> 16);
        }
    }
    for (; e + 4 <= e1; e += 4) {
        uint2 w[4];
#pragma unroll
        for (int j = 0; j < 4; ++j) w[j] = hv[(size_t)col[e + j] * 64 + lane];
#pragma unroll
        for (int j = 0; j < 4; ++j) {
            ax[j] += bf2f(w[j].x & 0xffffu); ay[j] += bf2f(w[j].x >> 16);
            az[j] += bf2f(w[j].y & 0xffffu); aw[j] += bf2f(w[j].y >> 16);
        }
    }
    for (; e < e1; ++e) {
        int j = e & 7;
        uint2 w0 = hv[(size_t)col[e] * 64 + lane];
        ax[j] += bf2f(w0.x & 0xffffu); ay[j] += bf2f(w0.x >> 16);
        az[j] += bf2f(w0.y & 0xffffu); aw[j] += bf2f(w0.y >> 16);
    }
    float r0 = ((ax[0] + ax[1]) + (ax[2] + ax[3])) + ((ax[4] + ax[5]) + (ax[6] + ax[7]));
    float r1 = ((ay[0] + ay[1]) + (ay[2] + ay[3])) + ((ay[4] + ay[5]) + (ay[6] + ay[7]));
    float r2 = ((az[0] + az[1]) + (az[2] + az[3])) + ((az[4] + az[5]) + (az[6] + az[7]));
    float r3 = ((aw[0] + aw[1]) + (aw[2] + aw[3])) + ((aw[4] + aw[5]) + (aw[6] + aw[7]));
    uint2 ov;
    ov.x = (unsigned)f2bf(r0) | ((unsigned)f2bf(r1) << 16);
    ov.y = (unsigned)f2bf(r2) | ((unsigned)f2bf(r3) << 16);
    ((uint2*)out)[(size_t)node * 64 + lane] = ov;
}

// ---------------- MFMA GEMM: whole Wt in LDS, A streamed global->VGPR, no K-loop barriers ----
// Block: 512 threads = 8 waves (2 row-waves x 4 col-waves), tile 128 rows x 256 cols, K=256.
__global__ __launch_bounds__(512, 2) void gemm_fused(const bf16u* __restrict__ A,
                                                     const bf16u* __restrict__ Wt,
                                                     const void* __restrict__ bias,
                                                     void* __restrict__ Cout, int mrows,
                                                     const int* __restrict__ flags,
                                                     int relu, int f32out,
                                                     float* __restrict__ stats) {
    __shared__ bf16u Bs[256 * 256];   // 128 KB, XOR-swizzled k-chunks
    __shared__ float lsum[512];       // [0..255] col sums, [256..511] col sumsq
    int isf32 = flags[0];
    int t = threadIdx.x;
    // stage all of Wt (256x256) into LDS, swizzle chunk c of row n to slot c^(n&7)
#pragma unroll
    for (int i = 0; i < 16; ++i) {
        int idx = i * 512 + t;          // 0..8191 chunks of 16B
        int n = idx >> 5, c = idx & 31;
        bf16x8s v = *(const bf16x8s*)(Wt + n * 256 + c * 8);
        *(bf16x8s*)&Bs[n * 256 + ((c ^ (n & 7)) * 8)] = v;
    }
    lsum[t < 512 ? t : 0] = 0.f;
    __syncthreads();

    int w = t >> 6, lane = t & 63;
    int lr = lane & 15, lq = lane >> 4;
    int wm = w & 1, wn = w >> 1;               // wm: row half, wn: col quarter
    int rowBase = blockIdx.x * 128;
    const bf16u* aptr[4];
#pragma unroll
    for (int mt = 0; mt < 4; ++mt) {
        int gr = rowBase + wm * 64 + mt * 16 + lr;
        gr = (gr < mrows) ? gr : (mrows - 1);
        aptr[mt] = A + (size_t)gr * 256 + lq * 8;
    }
    f32x4 acc[4][4] = {};
#pragma unroll
    for (int ks = 0; ks < 8; ++ks) {
        bf16x8s af[4], bfv[4];
#pragma unroll
        for (int mt = 0; mt < 4; ++mt)
            af[mt] = *(const bf16x8s*)(aptr[mt] + ks * 32);
#pragma unroll
        for (int nt = 0; nt < 4; ++nt) {
            int br = wn * 64 + nt * 16 + lr;
            bfv[nt] = *(const bf16x8s*)&Bs[br * 256 + (((ks * 4 + lq) ^ (lr & 7)) * 8)];
        }
#pragma unroll
        for (int mt = 0; mt < 4; ++mt)
#pragma unroll
            for (int nt = 0; nt < 4; ++nt)
                acc[mt][nt] = __builtin_amdgcn_mfma_f32_16x16x32_bf16(af[mt], bfv[nt], acc[mt][nt], 0, 0, 0);
    }
    int storef32 = f32out && isf32;
#pragma unroll
    for (int nt = 0; nt < 4; ++nt) {
        int c = wn * 64 + nt * 16 + lr;
        float bv = loadv(bias, c, isf32);
        float ssum = 0.f, ssq = 0.f;
#pragma unroll
        for (int mt = 0; mt < 4; ++mt) {
            int r0 = rowBase + wm * 64 + mt * 16 + lq * 4;
#pragma unroll
            for (int j = 0; j < 4; ++j) {
                int r = r0 + j;
                if (r < mrows) {
                    float y = acc[mt][nt][j] + bv;
                    if (relu) y = fmaxf(y, 0.f);
                    if (storef32) ((float*)Cout)[(size_t)r * 256 + c] = y;
                    else          ((bf16u*)Cout)[(size_t)r * 256 + c] = f2bf(y);
                    ssum += y; ssq += y * y;
                }
            }
        }
        if (stats) {
            atomicAdd(&lsum[c], ssum);
            atomicAdd(&lsum[256 + c], ssq);
        }
    }
    if (stats) {
        __syncthreads();
        atomicAdd(&stats[t], lsum[t]);
    }
}

extern "C" void kernel_launch(void* const* d_in, const int* in_sizes, int n_in,
                              void* d_out, int out_size, void* d_ws, size_t ws_size,
                              hipStream_t stream) {
    const void* x   = d_in[0];
    const int*  ei  = (const int*)d_in[1];
    const void* g0  = d_in[2];
    const void* b0  = d_in[3];
    const void* W1a = d_in[4];
    const void* b1a = d_in[5];
    const void* g1  = d_in[6];
    const void* bt1 = d_in[7];
    const void* W1b = d_in[8];
    const void* b1b = d_in[9];
    const void* W2a = d_in[10];
    const void* b2a = d_in[11];
    const void* g2  = d_in[12];
    const void* bt2 = d_in[13];
    const void* W2b = d_in[14];
    const void* b2b = d_in[15];

    char* ws = (char*)d_ws;
    size_t off = 0;
    auto alloc = [&](size_t bytes) {
        char* p = ws + off;
        off += (bytes + 255) & ~(size_t)255;
        return p;
    };
    const size_t FB = (size_t)N_NODES * DIM * 2;
    bf16u* bufA  = (bf16u*)alloc(FB);
    bf16u* bufB  = (bf16u*)alloc(FB);
    bf16u* Wt    = (bf16u*)alloc((size_t)4 * DIM * DIM * 2);
    int*   colA  = (int*)alloc((size_t)N_EDGES * 4);
    int*   rp    = (int*)alloc((size_t)(N_NODES + 1) * 4);
    int*   deg   = (int*)alloc((size_t)N_NODES * 4);
    int*   fill  = (int*)alloc((size_t)N_NODES * 4);
    int*   bsum  = (int*)alloc(512 * 4);
    float* sums0 = (float*)alloc(512 * 4);
    float* sums1 = (float*)alloc(512 * 4);
    float* sums2 = (float*)alloc(512 * 4);
    float* sc    = (float*)alloc(256 * 4);
    float* sh    = (float*)alloc(256 * 4);
    int*   flags = (int*)alloc(4 * 4);

    bf16u* Wt1a = Wt;
    bf16u* Wt1b = Wt + 65536;
    bf16u* Wt2a = Wt + 2 * 65536;
    bf16u* Wt2b = Wt + 3 * 65536;

    const float inv_n = 1.0f / (float)N_NODES;

    detect_flags<<<1, 256, 0, stream>>>((const unsigned*)x, ei, flags);
    zero_floats<<<6, 256, 0, stream>>>(sums0, 1536);   // sums0..sums2 contiguous
    transpose_w<<<dim3(16, 4), 256, 0, stream>>>(W1a, W1b, W2a, W2b, Wt, flags);

    zero_ints<<<391, 256, 0, stream>>>(deg, N_NODES);
    zero_ints<<<391, 256, 0, stream>>>(fill, N_NODES);
    edge_hist<<<6250, 256, 0, stream>>>(ei, flags, deg);
    scan1<<<391, 256, 0, stream>>>(deg, rp, bsum);
    scan2<<<1, 512, 0, stream>>>(bsum, 391);
    scan3<<<392, 256, 0, stream>>>(rp, bsum);
    csr_fill<<<6250, 256, 0, stream>>>(ei, flags, rp, fill, colA);

    // BN0: x (f32) -> bufB (bf16)
    col_stats<<<500, 256, 0, stream>>>(x, N_NODES, sums0, flags, 1);
    bn_finalize<<<1, 256, 0, stream>>>(sums0, g0, b0, sc, sh, inv_n, flags);
    bn_apply<<<12500, 256, 0, stream>>>(x, sc, sh, bufB, flags, 1, 0);

    // layer 1
    aggregate<<<25000, 256, 0, stream>>>(bufB, rp, colA, bufA);
    gemm_fused<<<782, 512, 0, stream>>>(bufA, Wt1a, b1a, bufB, N_NODES, flags, 0, 0, sums1);
    bn_finalize<<<1, 256, 0, stream>>>(sums1, g1, bt1, sc, sh, inv_n, flags);
    bn_apply<<<12500, 256, 0, stream>>>(bufB, sc, sh, bufB, flags, 0, 1);
    gemm_fused<<<782, 512, 0, stream>>>(bufB, Wt1b, b1b, bufA, N_NODES, flags, 1, 0, nullptr);

    // layer 2
    aggregate<<<25000, 256, 0, stream>>>(bufA, rp, colA, bufB);
    gemm_fused<<<782, 512, 0, stream>>>(bufB, Wt2a, b2a, bufA, N_NODES, flags, 0, 0, sums2);
    bn_finalize<<<1, 256, 0, stream>>>(sums2, g2, bt2, sc, sh, inv_n, flags);
    bn_apply<<<12500, 256, 0, stream>>>(bufA, sc, sh, bufA, flags, 0, 1);
    gemm_fused<<<782, 512, 0, stream>>>(bufA, Wt2b, b2b, d_out, N_NODES, flags, 1, 1, nullptr);
}